// Round 2
// baseline (3043.091 us; speedup 1.0000x reference)
//
#include <hip/hip_runtime.h>
#include <hip/hip_bf16.h>
#include <cmath>

// Problem constants
#define N_   128
#define T_   64
#define D_   1024
#define H_   1024
#define G4_  4096   // 4*H
#define KTOT 3072   // D + H + H (segments: x | h | attn)

typedef short bf16x8 __attribute__((ext_vector_type(8)));
typedef float f32x4  __attribute__((ext_vector_type(4)));

__device__ __forceinline__ unsigned short f2bf(float f) {
    union { float f; unsigned int u; } v; v.f = f;
    unsigned int r = (v.u + 0x7FFFu + ((v.u >> 16) & 1u)) >> 16;  // RNE
    return (unsigned short)r;
}

// ---------------------------------------------------------------- prep ----

__global__ void k_convert_x(const float* __restrict__ x, unsigned short* __restrict__ xbf) {
    long i = ((long)blockIdx.x * blockDim.x + threadIdx.x) * 8;
    float4 a = *(const float4*)(x + i);
    float4 b = *(const float4*)(x + i + 4);
    union { unsigned short s[8]; uint4 v; } o;
    o.s[0] = f2bf(a.x); o.s[1] = f2bf(a.y); o.s[2] = f2bf(a.z); o.s[3] = f2bf(a.w);
    o.s[4] = f2bf(b.x); o.s[5] = f2bf(b.y); o.s[6] = f2bf(b.z); o.s[7] = f2bf(b.w);
    *(uint4*)(xbf + i) = o.v;
}

// out[c][ocoff + r] = bf16(in[r][c]); in is R x C (f32), out rows have stride ors.
__global__ void k_transpose(const float* __restrict__ in, unsigned short* __restrict__ out,
                            int R, int C, long ors, long ocoff) {
    __shared__ float tile[32][33];
    int c0 = blockIdx.x * 32, r0 = blockIdx.y * 32;
    int tx = threadIdx.x, ty = threadIdx.y;  // (32, 8)
    for (int yy = ty; yy < 32; yy += 8) {
        int r = r0 + yy, c = c0 + tx;
        if (r < R && c < C) tile[yy][tx] = in[(long)r * C + c];
    }
    __syncthreads();
    for (int yy = ty; yy < 32; yy += 8) {
        int oc = c0 + yy;    // out row  (orig col)
        int orr = r0 + tx;   // out col  (orig row)
        if (oc < C && orr < R) out[(long)oc * ors + ocoff + orr] = f2bf(tile[tx][yy]);
    }
}

// h0[n][j] = mean_p A[n][j][p];  c0 = h0;  also bf16 copy
__global__ void k_h0(const float* __restrict__ A, float* __restrict__ h,
                     float* __restrict__ c, unsigned short* __restrict__ hbf) {
    long id = (long)blockIdx.x * blockDim.x + threadIdx.x;  // 0 .. 128*1024-1
    const float4* ap = (const float4*)(A + id * 16);
    float s = 0.f;
    #pragma unroll
    for (int q = 0; q < 4; q++) { float4 v = ap[q]; s += v.x + v.y + v.z + v.w; }
    float m = s * (1.0f / 16.0f);
    h[id] = m; c[id] = m; hbf[id] = f2bf(m);
}

// ------------------------------------------------------------- per step ----

// scores -> softmax -> attn (all fp32), emit attn as bf16. One block per n.
__global__ void k_score(const float* __restrict__ A, const float* __restrict__ h,
                        unsigned short* __restrict__ attnbf) {
    int n = blockIdx.x;
    int tid = threadIdx.x;  // 256
    const float* An = A + (long)n * (H_ * 16);
    const float* hn = h + (long)n * H_;

    float acc[16];
    #pragma unroll
    for (int p = 0; p < 16; p++) acc[p] = 0.f;
    #pragma unroll
    for (int u = 0; u < 4; u++) {
        int hh = tid * 4 + u;
        float hv = hn[hh];
        const float4* ap = (const float4*)(An + (long)hh * 16);
        #pragma unroll
        for (int q = 0; q < 4; q++) {
            float4 v = ap[q];
            acc[q*4+0] += hv * v.x; acc[q*4+1] += hv * v.y;
            acc[q*4+2] += hv * v.z; acc[q*4+3] += hv * v.w;
        }
    }
    __shared__ float red[256][16];
    #pragma unroll
    for (int p = 0; p < 16; p++) red[tid][p] = acc[p];
    __syncthreads();
    for (int s = 128; s > 0; s >>= 1) {
        if (tid < s) {
            #pragma unroll
            for (int p = 0; p < 16; p++) red[tid][p] += red[tid + s][p];
        }
        __syncthreads();
    }
    float w[16];
    {
        float m = -1e30f;
        #pragma unroll
        for (int p = 0; p < 16; p++) { w[p] = red[0][p] * (1.0f / 32.0f); m = fmaxf(m, w[p]); }
        float sum = 0.f;
        #pragma unroll
        for (int p = 0; p < 16; p++) { w[p] = expf(w[p] - m); sum += w[p]; }
        float inv = 1.0f / sum;
        #pragma unroll
        for (int p = 0; p < 16; p++) w[p] *= inv;
    }
    for (int hh = tid; hh < H_; hh += 256) {
        const float4* ap = (const float4*)(An + (long)hh * 16);
        float s = 0.f;
        #pragma unroll
        for (int q = 0; q < 4; q++) {
            float4 v = ap[q];
            s += w[q*4+0]*v.x + w[q*4+1]*v.y + w[q*4+2]*v.z + w[q*4+3]*v.w;
        }
        attnbf[(long)n * H_ + hh] = f2bf(s);
    }
}

// Fused gate GEMM: act = [xt|h|attn] @ Wt^T + b, then LSTM update.
// grid (4, 64), block 128 (2 waves). Wave tile: 16 rows(n) x 16 cols(jh) x 4 gates.
__global__ void k_step(const unsigned short* __restrict__ xbf,     // [N][T][D]
                       const unsigned short* __restrict__ hbf_in,  // [N][H]
                       const unsigned short* __restrict__ attnbf,  // [N][H]
                       const unsigned short* __restrict__ Wt,      // [4096][3072]
                       const float* __restrict__ bvec,             // [4096]
                       float* __restrict__ c, float* __restrict__ h,
                       unsigned short* __restrict__ hbf_out,
                       float* __restrict__ out, int t) {
    int wave = threadIdx.x >> 6;
    int lane = threadIdx.x & 63;
    int cl = lane & 15;   // MFMA col (jh within tile) / A-row within tile
    int kg = lane >> 4;   // MFMA k-group
    int rowbase = blockIdx.x * 32 + wave * 16;  // n base
    int colbase = blockIdx.y * 16;              // jh base

    f32x4 acc[4];
    #pragma unroll
    for (int g = 0; g < 4; g++) acc[g] = (f32x4){0.f, 0.f, 0.f, 0.f};

    int r = rowbase + cl;  // this lane's A row (n index)
    const unsigned short* abases[3];
    abases[0] = xbf + ((long)r * T_ + t) * D_ + kg * 8;
    abases[1] = hbf_in + (long)r * H_ + kg * 8;
    abases[2] = attnbf + (long)r * H_ + kg * 8;

    const unsigned short* bp[4];
    #pragma unroll
    for (int g = 0; g < 4; g++)
        bp[g] = Wt + (long)(g * 1024 + colbase + cl) * KTOT + kg * 8;

    #pragma unroll
    for (int seg = 0; seg < 3; seg++) {
        const unsigned short* ab = abases[seg];
        long koff = (long)seg * 1024;
        #pragma unroll 4
        for (int k0 = 0; k0 < 1024; k0 += 32) {
            bf16x8 a = *(const bf16x8*)(ab + k0);
            #pragma unroll
            for (int g = 0; g < 4; g++) {
                bf16x8 bb = *(const bf16x8*)(bp[g] + koff + k0);
                acc[g] = __builtin_amdgcn_mfma_f32_16x16x32_bf16(a, bb, acc[g], 0, 0, 0);
            }
        }
    }

    int jh = colbase + cl;
    float bi = bvec[jh], bfv = bvec[1024 + jh], bo = bvec[2048 + jh], bg = bvec[3072 + jh];
    #pragma unroll
    for (int v = 0; v < 4; v++) {
        int n = rowbase + kg * 4 + v;  // D row = 4*(lane>>4) + reg
        float xi = acc[0][v] + bi;
        float xf = acc[1][v] + bfv;
        float xo = acc[2][v] + bo;
        float xg = acc[3][v] + bg;
        float ig = 1.f / (1.f + expf(-xi));
        float fg = 1.f / (1.f + expf(-xf));
        float og = 1.f / (1.f + expf(-xo));
        float gg = tanhf(xg);
        long idx = (long)n * H_ + jh;
        float cn = fg * c[idx] + ig * gg;
        float hn = og * tanhf(cn);
        c[idx] = cn;
        h[idx] = hn;
        hbf_out[idx] = f2bf(hn);
        out[((long)n * T_ + t) * H_ + jh] = hn;
    }
}

// ---------------------------------------------------------------- launch ----

extern "C" void kernel_launch(void* const* d_in, const int* in_sizes, int n_in,
                              void* d_out, int out_size, void* d_ws, size_t ws_size,
                              hipStream_t stream) {
    const float* x     = (const float*)d_in[0];
    const float* A     = (const float*)d_in[1];
    const float* Wx    = (const float*)d_in[2];
    const float* Wh    = (const float*)d_in[3];
    const float* Wattn = (const float*)d_in[4];
    const float* b     = (const float*)d_in[5];
    float* out = (float*)d_out;

    char* ws = (char*)d_ws;
    size_t off = 0;
    auto alloc = [&](size_t bytes) -> void* {
        void* p = ws + off;
        off += (bytes + 255) & ~(size_t)255;
        return p;
    };
    unsigned short* xbf    = (unsigned short*)alloc((size_t)N_ * T_ * D_ * 2);
    unsigned short* Wt     = (unsigned short*)alloc((size_t)G4_ * KTOT * 2);
    float*          hbuf   = (float*)alloc((size_t)N_ * H_ * 4);
    float*          cbuf   = (float*)alloc((size_t)N_ * H_ * 4);
    unsigned short* hbf0   = (unsigned short*)alloc((size_t)N_ * H_ * 2);
    unsigned short* hbf1   = (unsigned short*)alloc((size_t)N_ * H_ * 2);
    unsigned short* attnbf = (unsigned short*)alloc((size_t)N_ * H_ * 2);

    // prep
    k_convert_x<<<dim3((N_ * T_ * D_) / (256 * 8)), dim3(256), 0, stream>>>(x, xbf);
    k_transpose<<<dim3(G4_ / 32, D_ / 32), dim3(32, 8), 0, stream>>>(Wx,    Wt, D_, G4_, (long)KTOT, 0L);
    k_transpose<<<dim3(G4_ / 32, H_ / 32), dim3(32, 8), 0, stream>>>(Wh,    Wt, H_, G4_, (long)KTOT, 1024L);
    k_transpose<<<dim3(G4_ / 32, H_ / 32), dim3(32, 8), 0, stream>>>(Wattn, Wt, H_, G4_, (long)KTOT, 2048L);
    k_h0<<<dim3((N_ * H_) / 256), dim3(256), 0, stream>>>(A, hbuf, cbuf, hbf0);

    // recurrence
    for (int t = 0; t < T_; t++) {
        unsigned short* hin  = (t & 1) ? hbf1 : hbf0;
        unsigned short* hout = (t & 1) ? hbf0 : hbf1;
        k_score<<<dim3(N_), dim3(256), 0, stream>>>(A, hbuf, attnbf);
        k_step<<<dim3(4, 64), dim3(128), 0, stream>>>(xbf, hin, attnbf, Wt, b,
                                                      cbuf, hbuf, hout, out, t);
    }
}

// Round 3
// 1683.871 us; speedup vs baseline: 1.8072x; 1.8072x over previous
//
#include <hip/hip_runtime.h>
#include <hip/hip_bf16.h>
#include <cmath>

// Problem constants
#define N_   128
#define T_   64
#define D_   1024
#define H_   1024
#define G4_  4096   // 4*H
#define KTOT 3072   // D + H + H (segments: x | h | attn)

typedef short bf16x8 __attribute__((ext_vector_type(8)));
typedef float f32x4  __attribute__((ext_vector_type(4)));

__device__ __forceinline__ unsigned short f2bf(float f) {
    union { float f; unsigned int u; } v; v.f = f;
    unsigned int r = (v.u + 0x7FFFu + ((v.u >> 16) & 1u)) >> 16;  // RNE
    return (unsigned short)r;
}

// ---------------------------------------------------------------- prep ----

__global__ void k_convert_x(const float* __restrict__ x, unsigned short* __restrict__ xbf) {
    long i = ((long)blockIdx.x * blockDim.x + threadIdx.x) * 8;
    float4 a = *(const float4*)(x + i);
    float4 b = *(const float4*)(x + i + 4);
    union { unsigned short s[8]; uint4 v; } o;
    o.s[0] = f2bf(a.x); o.s[1] = f2bf(a.y); o.s[2] = f2bf(a.z); o.s[3] = f2bf(a.w);
    o.s[4] = f2bf(b.x); o.s[5] = f2bf(b.y); o.s[6] = f2bf(b.z); o.s[7] = f2bf(b.w);
    *(uint4*)(xbf + i) = o.v;
}

// out[c][ocoff + r] = bf16(in[r][c]); in is R x C (f32), out rows have stride ors.
__global__ void k_transpose(const float* __restrict__ in, unsigned short* __restrict__ out,
                            int R, int C, long ors, long ocoff) {
    __shared__ float tile[32][33];
    int c0 = blockIdx.x * 32, r0 = blockIdx.y * 32;
    int tx = threadIdx.x, ty = threadIdx.y;  // (32, 8)
    for (int yy = ty; yy < 32; yy += 8) {
        int r = r0 + yy, c = c0 + tx;
        if (r < R && c < C) tile[yy][tx] = in[(long)r * C + c];
    }
    __syncthreads();
    for (int yy = ty; yy < 32; yy += 8) {
        int oc = c0 + yy;    // out row  (orig col)
        int orr = r0 + tx;   // out col  (orig row)
        if (oc < C && orr < R) out[(long)oc * ors + ocoff + orr] = f2bf(tile[tx][yy]);
    }
}

// h0[n][j] = mean_p A[n][j][p];  c0 = h0;  also bf16 copy
__global__ void k_h0(const float* __restrict__ A, float* __restrict__ h,
                     float* __restrict__ c, unsigned short* __restrict__ hbf) {
    long id = (long)blockIdx.x * blockDim.x + threadIdx.x;  // 0 .. 128*1024-1
    const float4* ap = (const float4*)(A + id * 16);
    float s = 0.f;
    #pragma unroll
    for (int q = 0; q < 4; q++) { float4 v = ap[q]; s += v.x + v.y + v.z + v.w; }
    float m = s * (1.0f / 16.0f);
    h[id] = m; c[id] = m; hbf[id] = f2bf(m);
}

// ------------------------------------------------------------- per step ----

// scores -> softmax -> attn (fp32). One block (512 thr) per n; A read ONCE,
// rows kept in registers for the weighted-sum pass.
__global__ __launch_bounds__(512)
void k_score(const float* __restrict__ A, const float* __restrict__ h,
             unsigned short* __restrict__ attnbf) {
    int n = blockIdx.x;
    int tid = threadIdx.x;            // 0..511
    int wave = tid >> 6, lane = tid & 63;
    const float* An = A + (long)n * (H_ * 16);
    const float* hn = h + (long)n * H_;

    int h0 = tid * 2;                 // this thread's two H rows
    float4 row[2][4];
    float acc[16];
    #pragma unroll
    for (int p = 0; p < 16; p++) acc[p] = 0.f;
    #pragma unroll
    for (int u = 0; u < 2; u++) {
        float hv = hn[h0 + u];
        const float4* ap = (const float4*)(An + (long)(h0 + u) * 16);
        #pragma unroll
        for (int q = 0; q < 4; q++) {
            float4 v = ap[q];
            row[u][q] = v;
            acc[q*4+0] += hv * v.x; acc[q*4+1] += hv * v.y;
            acc[q*4+2] += hv * v.z; acc[q*4+3] += hv * v.w;
        }
    }
    // wave shuffle reduce (64 lanes)
    #pragma unroll
    for (int off = 32; off > 0; off >>= 1) {
        #pragma unroll
        for (int p = 0; p < 16; p++) acc[p] += __shfl_xor(acc[p], off);
    }
    __shared__ float sred[8][16];
    __shared__ float wsh[16];
    if (lane == 0) {
        #pragma unroll
        for (int p = 0; p < 16; p++) sred[wave][p] = acc[p];
    }
    __syncthreads();
    if (tid < 16) {
        float s = 0.f;
        #pragma unroll
        for (int w = 0; w < 8; w++) s += sred[w][tid];
        wsh[tid] = s * (1.0f / 32.0f);   // /sqrt(H)
    }
    __syncthreads();
    float w[16];
    {
        float m = -1e30f;
        #pragma unroll
        for (int p = 0; p < 16; p++) { w[p] = wsh[p]; m = fmaxf(m, w[p]); }
        float sum = 0.f;
        #pragma unroll
        for (int p = 0; p < 16; p++) { w[p] = expf(w[p] - m); sum += w[p]; }
        float inv = 1.0f / sum;
        #pragma unroll
        for (int p = 0; p < 16; p++) w[p] *= inv;
    }
    #pragma unroll
    for (int u = 0; u < 2; u++) {
        float s = 0.f;
        #pragma unroll
        for (int q = 0; q < 4; q++) {
            float4 v = row[u][q];
            s += w[q*4+0]*v.x + w[q*4+1]*v.y + w[q*4+2]*v.z + w[q*4+3]*v.w;
        }
        attnbf[(long)n * H_ + h0 + u] = f2bf(s);
    }
}

// Fused gate GEMM: act = [xt|h|attn] @ Wt^T + b, then LSTM update.
// grid (64 col-tiles, 4 row-tiles), block 512 = 8 waves (K-split 8).
// Wave tile: 32 rows (R=2 B-reuse) x 16 cols x 4 gates over K=384.
// grid.x = col-tile -> XCD = cx%8: per-XCD Wt slice (3.1MB) identical every
// step -> cross-step L2 residency; all 4 row-blocks of a column share one L2.
__global__ __launch_bounds__(512)
void k_step(const unsigned short* __restrict__ xbf,     // [N][T][D]
            const unsigned short* __restrict__ hbf_in,  // [N][H]
            const unsigned short* __restrict__ attnbf,  // [N][H]
            const unsigned short* __restrict__ Wt,      // [4096][3072]
            const float* __restrict__ bvec,             // [4096]
            float* __restrict__ c, float* __restrict__ h,
            unsigned short* __restrict__ hbf_out,
            float* __restrict__ out, int t) {
    int wave = threadIdx.x >> 6;   // 0..7 = K-split index
    int lane = threadIdx.x & 63;
    int cl = lane & 15;            // MFMA col / A-row within subtile
    int kg = lane >> 4;            // MFMA k-group
    int colbase = blockIdx.x * 16; // jh base
    int rowbase = blockIdx.y * 32; // n base (2 subtiles of 16)

    f32x4 acc[4][2];
    #pragma unroll
    for (int g = 0; g < 4; g++) {
        acc[g][0] = (f32x4){0.f,0.f,0.f,0.f};
        acc[g][1] = (f32x4){0.f,0.f,0.f,0.f};
    }

    int kw = wave * 128;           // this wave's k-window within each segment
    int r0 = rowbase + cl;
    const unsigned short* a0[3];
    a0[0] = xbf    + ((long)r0 * T_ + t) * D_ + kw + kg * 8;
    a0[1] = hbf_in + (long)r0 * H_          + kw + kg * 8;
    a0[2] = attnbf + (long)r0 * H_          + kw + kg * 8;
    const long rs[3] = {16L * T_ * D_, 16L * H_, 16L * H_};

    const unsigned short* bp[4];
    #pragma unroll
    for (int g = 0; g < 4; g++)
        bp[g] = Wt + (long)(g * 1024 + colbase + cl) * KTOT + kw + kg * 8;

    #pragma unroll
    for (int seg = 0; seg < 3; seg++) {
        const unsigned short* ab = a0[seg];
        long rstep = rs[seg];
        long koff = (long)seg * 1024;
        #pragma unroll
        for (int k0 = 0; k0 < 128; k0 += 32) {
            bf16x8 a1 = *(const bf16x8*)(ab + k0);
            bf16x8 a2 = *(const bf16x8*)(ab + rstep + k0);
            #pragma unroll
            for (int g = 0; g < 4; g++) {
                bf16x8 bb = *(const bf16x8*)(bp[g] + koff + k0);
                acc[g][0] = __builtin_amdgcn_mfma_f32_16x16x32_bf16(a1, bb, acc[g][0], 0, 0, 0);
                acc[g][1] = __builtin_amdgcn_mfma_f32_16x16x32_bf16(a2, bb, acc[g][1], 0, 0, 0);
            }
        }
    }

    // ---- cross-wave K reduction (pairwise to keep LDS < 64KB) ----
    __shared__ float red[4][64][33];
    if (wave >= 4) {
        #pragma unroll
        for (int g = 0; g < 4; g++)
            #pragma unroll
            for (int rh = 0; rh < 2; rh++)
                #pragma unroll
                for (int v = 0; v < 4; v++)
                    red[wave - 4][lane][g*8 + rh*4 + v] = acc[g][rh][v];
    }
    __syncthreads();
    if (wave < 4) {
        #pragma unroll
        for (int g = 0; g < 4; g++)
            #pragma unroll
            for (int rh = 0; rh < 2; rh++)
                #pragma unroll
                for (int v = 0; v < 4; v++)
                    acc[g][rh][v] += red[wave][lane][g*8 + rh*4 + v];
    }
    __syncthreads();
    if (wave < 4) {
        #pragma unroll
        for (int g = 0; g < 4; g++)
            #pragma unroll
            for (int rh = 0; rh < 2; rh++)
                #pragma unroll
                for (int v = 0; v < 4; v++)
                    red[wave][lane][g*8 + rh*4 + v] = acc[g][rh][v];
    }
    __syncthreads();

    // ---- balanced epilogue: 512 threads x 1 output element ----
    int tt = threadIdx.x;
    int r  = tt >> 4;          // 0..31 local row
    int cc = tt & 15;          // local col
    int rh = r >> 4;
    int r16 = r & 15;          // = 4*kg2 + v2 (subtile row mapping)
    int kg2 = r16 >> 2, v2 = r16 & 3;
    int ln = kg2 * 16 + cc;
    int idx0 = rh * 4 + v2;
    float s[4];
    #pragma unroll
    for (int g = 0; g < 4; g++) {
        float a = 0.f;
        #pragma unroll
        for (int w = 0; w < 4; w++) a += red[w][ln][g*8 + idx0];
        s[g] = a;
    }
    int jh = colbase + cc;
    int n  = rowbase + r;
    float xi = s[0] + bvec[jh];
    float xf = s[1] + bvec[1024 + jh];
    float xo = s[2] + bvec[2048 + jh];
    float xg = s[3] + bvec[3072 + jh];
    float ig = 1.f / (1.f + expf(-xi));
    float fg = 1.f / (1.f + expf(-xf));
    float og = 1.f / (1.f + expf(-xo));
    float gg = tanhf(xg);
    long idx = (long)n * H_ + jh;
    float cn = fg * c[idx] + ig * gg;
    float hn = og * tanhf(cn);
    c[idx] = cn;
    h[idx] = hn;
    hbf_out[idx] = f2bf(hn);
    out[((long)n * T_ + t) * H_ + jh] = hn;
}

// ---------------------------------------------------------------- launch ----

extern "C" void kernel_launch(void* const* d_in, const int* in_sizes, int n_in,
                              void* d_out, int out_size, void* d_ws, size_t ws_size,
                              hipStream_t stream) {
    const float* x     = (const float*)d_in[0];
    const float* A     = (const float*)d_in[1];
    const float* Wx    = (const float*)d_in[2];
    const float* Wh    = (const float*)d_in[3];
    const float* Wattn = (const float*)d_in[4];
    const float* b     = (const float*)d_in[5];
    float* out = (float*)d_out;

    char* ws = (char*)d_ws;
    size_t off = 0;
    auto alloc = [&](size_t bytes) -> void* {
        void* p = ws + off;
        off += (bytes + 255) & ~(size_t)255;
        return p;
    };
    unsigned short* xbf    = (unsigned short*)alloc((size_t)N_ * T_ * D_ * 2);
    unsigned short* Wt     = (unsigned short*)alloc((size_t)G4_ * KTOT * 2);
    float*          hbuf   = (float*)alloc((size_t)N_ * H_ * 4);
    float*          cbuf   = (float*)alloc((size_t)N_ * H_ * 4);
    unsigned short* hbf0   = (unsigned short*)alloc((size_t)N_ * H_ * 2);
    unsigned short* hbf1   = (unsigned short*)alloc((size_t)N_ * H_ * 2);
    unsigned short* attnbf = (unsigned short*)alloc((size_t)N_ * H_ * 2);

    // prep
    k_convert_x<<<dim3((N_ * T_ * D_) / (256 * 8)), dim3(256), 0, stream>>>(x, xbf);
    k_transpose<<<dim3(G4_ / 32, D_ / 32), dim3(32, 8), 0, stream>>>(Wx,    Wt, D_, G4_, (long)KTOT, 0L);
    k_transpose<<<dim3(G4_ / 32, H_ / 32), dim3(32, 8), 0, stream>>>(Wh,    Wt, H_, G4_, (long)KTOT, 1024L);
    k_transpose<<<dim3(G4_ / 32, H_ / 32), dim3(32, 8), 0, stream>>>(Wattn, Wt, H_, G4_, (long)KTOT, 2048L);
    k_h0<<<dim3((N_ * H_) / 256), dim3(256), 0, stream>>>(A, hbuf, cbuf, hbf0);

    // recurrence
    for (int t = 0; t < T_; t++) {
        unsigned short* hin  = (t & 1) ? hbf1 : hbf0;
        unsigned short* hout = (t & 1) ? hbf0 : hbf1;
        k_score<<<dim3(N_), dim3(512), 0, stream>>>(A, hbuf, attnbf);
        k_step<<<dim3(64, 4), dim3(512), 0, stream>>>(xbf, hin, attnbf, Wt, b,
                                                      cbuf, hbuf, hout, out, t);
    }
}